// Round 1
// baseline (136.076 us; speedup 1.0000x reference)
//
#include <hip/hip_runtime.h>
#include <math.h>

#define BM 64
#define BN 64
#define BK 16

__device__ __forceinline__ float sigmoidf_(float v) {
    return 1.f / (1.f + expf(-v));
}

// y4[b, co, p] = bias[co] + sum_ci w[co,ci] * x4[b,ci,p]
// M=512 (co), N=256 (p), K=2048 (ci), per batch b (grid z).
__global__ __launch_bounds__(256) void conv1x1_gemm(
    const float* __restrict__ x4, const float* __restrict__ w,
    const float* __restrict__ bias, float* __restrict__ y4)
{
    const int b  = blockIdx.z;
    const int m0 = blockIdx.y * BM;  // co tile
    const int n0 = blockIdx.x * BN;  // p tile
    const int tx = threadIdx.x;      // 0..15 -> n
    const int ty = threadIdx.y;      // 0..15 -> m
    const int tid = ty * 16 + tx;

    __shared__ float As[2][BK][BM];  // [buf][k][m]
    __shared__ float Bs[2][BK][BN];  // [buf][k][n]

    const float* A    = w  + m0 * 2048;                 // A[m][k], row stride 2048
    const float* Bmat = x4 + (size_t)b * 2048 * 256 + n0; // B[k][n], row stride 256

    // load assignments
    const int ar = tid >> 2;            // 0..63  (m within tile)
    const int ak = (tid & 3) * 4;       // 0,4,8,12 (k within tile)
    const int br = tid >> 4;            // 0..15  (k within tile)
    const int bn = (tid & 15) * 4;      // 0..60  (n within tile)

    const float* Aptr = A + ar * 2048 + ak;
    const float* Bptr = Bmat + br * 256 + bn;

    float4 va = *(const float4*)(Aptr);
    float4 vb = *(const float4*)(Bptr);

    float acc[4][4] = {};

    for (int t = 0; t < 2048 / BK; ++t) {
        const int cur = t & 1;
        As[cur][ak + 0][ar] = va.x;
        As[cur][ak + 1][ar] = va.y;
        As[cur][ak + 2][ar] = va.z;
        As[cur][ak + 3][ar] = va.w;
        *(float4*)(&Bs[cur][br][bn]) = vb;
        __syncthreads();
        if (t < 2048 / BK - 1) {
            va = *(const float4*)(Aptr + (t + 1) * BK);
            vb = *(const float4*)(Bptr + (t + 1) * BK * 256);
        }
#pragma unroll
        for (int kk = 0; kk < BK; ++kk) {
            float a[4], bb[4];
            *(float4*)a  = *(const float4*)(&As[cur][kk][ty * 4]);
            *(float4*)bb = *(const float4*)(&Bs[cur][kk][tx * 4]);
#pragma unroll
            for (int i = 0; i < 4; ++i)
#pragma unroll
                for (int j = 0; j < 4; ++j)
                    acc[i][j] = fmaf(a[i], bb[j], acc[i][j]);
        }
        __syncthreads();
    }

#pragma unroll
    for (int i = 0; i < 4; ++i) {
        const int m = m0 + ty * 4 + i;
        const float bv = bias[m];
        float4 o;
        o.x = acc[i][0] + bv;
        o.y = acc[i][1] + bv;
        o.z = acc[i][2] + bv;
        o.w = acc[i][3] + bv;
        *(float4*)(y4 + (size_t)b * 512 * 256 + m * 256 + n0 + tx * 4) = o;
    }
}

// Channel attention per (b,g): avg over p, fc1(256->64)+relu, fc2(64->256)+sigmoid
__global__ __launch_bounds__(256) void ca_kernel(
    const float* __restrict__ y4,
    const float* __restrict__ fc1w, const float* __restrict__ fc1b,
    const float* __restrict__ fc2w, const float* __restrict__ fc2b,
    float* __restrict__ ca)
{
    const int bg = blockIdx.x;
    const int b = bg >> 3, g = bg & 7;
    const int c = threadIdx.x;
    const float* xg = y4 + (size_t)b * 512 * 256 + (g & 1) * 256 * 256;

    __shared__ float avgs[256];
    __shared__ float hs[64];

    const float* row = xg + c * 256;
    float s = 0.f;
    for (int p = 0; p < 256; p += 4) {
        float4 v = *(const float4*)(row + p);
        s += v.x + v.y + v.z + v.w;
    }
    avgs[c] = s * (1.f / 256.f);
    __syncthreads();

    if (c < 64) {
        const float* wr = fc1w + (g * 64 + c) * 256;
        float a = fc1b[g * 64 + c];
        for (int i = 0; i < 256; ++i) a = fmaf(avgs[i], wr[i], a);
        hs[c] = fmaxf(a, 0.f);
    }
    __syncthreads();

    const float* w2 = fc2w + (g * 256 + c) * 64;
    float a2 = fc2b[g * 256 + c];
    for (int o = 0; o < 64; ++o) a2 = fmaf(hs[o], w2[o], a2);
    ca[bg * 256 + c] = sigmoidf_(a2);
}

// Spatial attention + group sum of sigmoid(x*ca*sa)
__global__ __launch_bounds__(256) void sa_kernel(
    const float* __restrict__ y4, const float* __restrict__ ca,
    const float* __restrict__ saw, const float* __restrict__ sab,
    float* __restrict__ sa, float* __restrict__ gsum)
{
    const int bg = blockIdx.x;
    const int b = bg >> 3, g = bg & 7;
    const int p = threadIdx.x;
    const float* xg = y4 + (size_t)b * 512 * 256 + (g & 1) * 256 * 256;

    __shared__ float cav[256], caw[256];
    cav[p] = ca[bg * 256 + p];
    caw[p] = cav[p] * saw[g * 256 + p];
    __syncthreads();

    float acc = 0.f;
    for (int c = 0; c < 256; ++c) acc = fmaf(xg[c * 256 + p], caw[c], acc);
    const float sv = sigmoidf_(acc + sab[g]);
    sa[bg * 256 + p] = sv;

    float s = 0.f;
    for (int c = 0; c < 256; ++c) {
        float t = xg[c * 256 + p] * cav[c] * sv;
        s += sigmoidf_(t);
    }

    __shared__ float red[256];
    red[p] = s;
    __syncthreads();
    for (int off = 128; off > 0; off >>= 1) {
        if (p < off) red[p] += red[p + off];
        __syncthreads();
    }
    if (p == 0) gsum[bg] = red[0];
}

// out[b, ch, p] = x*(1+mask), mask = (y>mean) ? 1 : y, y = sigmoid(x*ca*sa)
__global__ __launch_bounds__(256) void final_kernel(
    const float* __restrict__ y4, const float* __restrict__ ca,
    const float* __restrict__ sa, const float* __restrict__ gsum,
    float* __restrict__ out)
{
    const int ch = blockIdx.x;           // 0..2047
    const int b = blockIdx.y;            // 0..7
    const int g = ch >> 8, c = ch & 255;
    const int bg = b * 8 + g;
    const int p = threadIdx.x;

    const float x = y4[(size_t)b * 512 * 256 + ((g & 1) * 256 + c) * 256 + p];
    const float yv = sigmoidf_(x * ca[bg * 256 + c] * sa[bg * 256 + p]);
    const float mean = gsum[bg] * (1.f / 65536.f);
    const float mask = (yv > mean) ? 1.f : yv;
    out[((size_t)b * 2048 + ch) * 256 + p] = x * (1.f + mask);
}

extern "C" void kernel_launch(void* const* d_in, const int* in_sizes, int n_in,
                              void* d_out, int out_size, void* d_ws, size_t ws_size,
                              hipStream_t stream) {
    const float* x4   = (const float*)d_in[3];
    const float* w4   = (const float*)d_in[10];
    const float* b4   = (const float*)d_in[11];
    const float* fc1w = (const float*)d_in[12];
    const float* fc1b = (const float*)d_in[13];
    const float* fc2w = (const float*)d_in[14];
    const float* fc2b = (const float*)d_in[15];
    const float* saw  = (const float*)d_in[16];
    const float* sab  = (const float*)d_in[17];
    float* out = (float*)d_out;

    float* ws   = (float*)d_ws;
    float* y4   = ws;                          // 8*512*256 = 1048576 floats
    float* ca   = ws + 1048576;                // 64*256 = 16384
    float* sa   = ws + 1048576 + 16384;        // 64*256 = 16384
    float* gsum = ws + 1048576 + 2 * 16384;    // 64

    conv1x1_gemm<<<dim3(256 / BN, 512 / BM, 8), dim3(16, 16), 0, stream>>>(x4, w4, b4, y4);
    ca_kernel<<<dim3(64), dim3(256), 0, stream>>>(y4, fc1w, fc1b, fc2w, fc2b, ca);
    sa_kernel<<<dim3(64), dim3(256), 0, stream>>>(y4, ca, saw, sab, sa, gsum);
    final_kernel<<<dim3(2048, 8), dim3(256), 0, stream>>>(y4, ca, sa, gsum, out);
}

// Round 2
// 78.115 us; speedup vs baseline: 1.7420x; 1.7420x over previous
//
#include <hip/hip_runtime.h>
#include <math.h>

typedef __attribute__((ext_vector_type(8))) short bf16x8;
typedef __attribute__((ext_vector_type(4))) float f32x4;

#define GK 2048

__device__ __forceinline__ unsigned short f2bf(float f) {
    unsigned int u = __builtin_bit_cast(unsigned int, f);
    unsigned int r = (u + 0x7FFFu + ((u >> 16) & 1)) >> 16;
    return (unsigned short)r;
}

__device__ __forceinline__ float sigmoidf_(float v) {
    return 1.f / (1.f + expf(-v));
}

// w [512][2048] fp32 -> bf16 same layout
__global__ __launch_bounds__(256) void convert_w(const float* __restrict__ w,
                                                 unsigned short* __restrict__ wbf) {
    int f = blockIdx.x * 256 + threadIdx.x;   // 0..262143 float4s
    float4 v = ((const float4*)w)[f];
    ushort4 o;
    o.x = f2bf(v.x); o.y = f2bf(v.y); o.z = f2bf(v.z); o.w = f2bf(v.w);
    ((ushort4*)wbf)[f] = o;
}

// x4 [8][2048][256] fp32 -> x_bfT [8][256][2048] bf16 (transpose via LDS)
__global__ __launch_bounds__(256) void transpose_x(const float* __restrict__ x4,
                                                   unsigned short* __restrict__ xbT) {
    __shared__ float t[64][65];
    const int b = blockIdx.z;
    const int ci0 = blockIdx.x * 64;   // 0..2047
    const int p0 = blockIdx.y * 64;    // 0..255
    const float* src = x4 + ((size_t)b * 2048 + ci0) * 256 + p0;
#pragma unroll
    for (int i = 0; i < 16; ++i) {
        int f = i * 256 + threadIdx.x;
        int ci = f >> 6, p = f & 63;
        t[p][ci] = src[ci * 256 + p];
    }
    __syncthreads();
    unsigned short* dst = xbT + ((size_t)b * 256 + p0) * 2048 + ci0;
#pragma unroll
    for (int i = 0; i < 8; ++i) {
        int f = i * 256 + threadIdx.x;
        int p = f >> 5, c2 = f & 31;
        ushort2 o;
        o.x = f2bf(t[p][c2 * 2]);
        o.y = f2bf(t[p][c2 * 2 + 1]);
        *(ushort2*)(dst + p * 2048 + c2 * 2) = o;
    }
}

// y4[b][m][n] = bias[m] + sum_k wbf[m][k] * xbT[b][n][k]
// M=512, N=256, K=2048; tile 64x64, BK=64; 4 waves, each 32x32.
__global__ __launch_bounds__(256) void gemm_bf16(
    const unsigned short* __restrict__ wbf, const unsigned short* __restrict__ xbT,
    const float* __restrict__ bias, float* __restrict__ y4)
{
    __shared__ short As[2][4096];   // [64 rows][64 k] swizzled, 8 KB per buf
    __shared__ short Bs[2][4096];

    const int tid = threadIdx.x;
    const int wave = tid >> 6, lane = tid & 63;
    const int wm = wave >> 1, wn = wave & 1;
    const int lr = lane & 15, lh = lane >> 4;   // frag row/col, k-group

    const int b = blockIdx.z, m0 = blockIdx.y * 64, n0 = blockIdx.x * 64;
    const unsigned short* Ag = wbf + (size_t)m0 * GK;
    const unsigned short* Bg = xbT + ((size_t)b * 256 + n0) * GK;

    // staging assignment: f = q*256+tid -> chunk (r = f>>3, c = f&7), 8 bf16 per chunk
    const int r0 = tid >> 3;         // q adds 32
    const int c0 = tid & 7;

    bf16x8 ra[2], rb[2];
    // prefetch tile 0
#pragma unroll
    for (int q = 0; q < 2; ++q) {
        int r = r0 + q * 32;
        ra[q] = *(const bf16x8*)(Ag + (size_t)r * GK + c0 * 8);
        rb[q] = *(const bf16x8*)(Bg + (size_t)r * GK + c0 * 8);
    }

    f32x4 acc[2][2] = {};
    int cur = 0;

    for (int t = 0; t < GK / 64; ++t) {
        // write staged regs into LDS (swizzled: chunk' = c ^ (r&7))
#pragma unroll
        for (int q = 0; q < 2; ++q) {
            int r = r0 + q * 32;
            int cp = c0 ^ (r & 7);
            *(bf16x8*)(&As[cur][r * 64 + cp * 8]) = ra[q];
            *(bf16x8*)(&Bs[cur][r * 64 + cp * 8]) = rb[q];
        }
        __syncthreads();
        // prefetch next tile into regs (overlaps with MFMA below)
        if (t < GK / 64 - 1) {
            int k0 = (t + 1) * 64;
#pragma unroll
            for (int q = 0; q < 2; ++q) {
                int r = r0 + q * 32;
                ra[q] = *(const bf16x8*)(Ag + (size_t)r * GK + k0 + c0 * 8);
                rb[q] = *(const bf16x8*)(Bg + (size_t)r * GK + k0 + c0 * 8);
            }
        }
#pragma unroll
        for (int kc = 0; kc < 2; ++kc) {
            const int ch = kc * 4 + lh;
            int rA0 = wm * 32 + lr,      rA1 = wm * 32 + 16 + lr;
            int rB0 = wn * 32 + lr,      rB1 = wn * 32 + 16 + lr;
            bf16x8 a0 = *(const bf16x8*)(&As[cur][rA0 * 64 + (ch ^ (rA0 & 7)) * 8]);
            bf16x8 a1 = *(const bf16x8*)(&As[cur][rA1 * 64 + (ch ^ (rA1 & 7)) * 8]);
            bf16x8 b0 = *(const bf16x8*)(&Bs[cur][rB0 * 64 + (ch ^ (rB0 & 7)) * 8]);
            bf16x8 b1 = *(const bf16x8*)(&Bs[cur][rB1 * 64 + (ch ^ (rB1 & 7)) * 8]);
            acc[0][0] = __builtin_amdgcn_mfma_f32_16x16x32_bf16(a0, b0, acc[0][0], 0, 0, 0);
            acc[0][1] = __builtin_amdgcn_mfma_f32_16x16x32_bf16(a0, b1, acc[0][1], 0, 0, 0);
            acc[1][0] = __builtin_amdgcn_mfma_f32_16x16x32_bf16(a1, b0, acc[1][0], 0, 0, 0);
            acc[1][1] = __builtin_amdgcn_mfma_f32_16x16x32_bf16(a1, b1, acc[1][1], 0, 0, 0);
        }
        __syncthreads();
        cur ^= 1;
    }

    float* yb = y4 + ((size_t)b * 512 + m0) * 256 + n0;
#pragma unroll
    for (int i = 0; i < 2; ++i) {
#pragma unroll
        for (int j = 0; j < 2; ++j) {
#pragma unroll
            for (int rr = 0; rr < 4; ++rr) {
                int m = wm * 32 + i * 16 + lh * 4 + rr;
                int n = wn * 32 + j * 16 + lr;
                yb[m * 256 + n] = acc[i][j][rr] + bias[m0 + m];
            }
        }
    }
}

// Fused channel + spatial attention per (b,g): 64 blocks x 512 threads
__global__ __launch_bounds__(512) void att_kernel(
    const float* __restrict__ y4,
    const float* __restrict__ fc1w, const float* __restrict__ fc1b,
    const float* __restrict__ fc2w, const float* __restrict__ fc2b,
    const float* __restrict__ saw, const float* __restrict__ sab,
    float* __restrict__ ca, float* __restrict__ sa, float* __restrict__ gsum)
{
    const int bg = blockIdx.x, b = bg >> 3, g = bg & 7;
    const int tid = threadIdx.x;
    const float* xg = y4 + ((size_t)b * 512 + (g & 1) * 256) * 256;

    __shared__ float red[512];
    __shared__ float avgs[256];
    __shared__ float hs[64];
    __shared__ float cas[256], caws[256], sas[256];

    // Phase A: per-channel mean over 256 positions
    {
        int c = tid >> 1, h = tid & 1;
        const float* row = xg + c * 256 + h * 128;
        float s = 0.f;
#pragma unroll
        for (int i = 0; i < 32; ++i) {
            float4 v = *(const float4*)(row + i * 4);
            s += v.x + v.y + v.z + v.w;
        }
        red[tid] = s;
    }
    __syncthreads();
    if (tid < 256) avgs[tid] = (red[tid * 2] + red[tid * 2 + 1]) * (1.f / 256.f);
    __syncthreads();

    // Phase B: fc1 (256 -> 64) + relu
    {
        int o = tid & 63, seg = tid >> 6;   // 8 segs x 32 elems
        const float* wr = fc1w + (g * 64 + o) * 256 + seg * 32;
        const float* av = avgs + seg * 32;
        float s = 0.f;
#pragma unroll
        for (int i = 0; i < 32; ++i) s = fmaf(av[i], wr[i], s);
        red[tid] = s;
    }
    __syncthreads();
    if (tid < 64) {
        float s = fc1b[g * 64 + tid];
#pragma unroll
        for (int k = 0; k < 8; ++k) s += red[k * 64 + tid];
        hs[tid] = fmaxf(s, 0.f);
    }
    __syncthreads();

    // Phase C: fc2 (64 -> 256) + sigmoid
    {
        int o = tid & 255, seg = tid >> 8;  // 2 segs x 32 elems
        const float* wr = fc2w + (g * 256 + o) * 64 + seg * 32;
        float s = 0.f;
#pragma unroll
        for (int i = 0; i < 32; ++i) s = fmaf(hs[seg * 32 + i], wr[i], s);
        red[tid] = s;
    }
    __syncthreads();
    if (tid < 256) {
        float v = sigmoidf_(red[tid] + red[256 + tid] + fc2b[g * 256 + tid]);
        cas[tid] = v;
        caws[tid] = v * saw[g * 256 + tid];
        ca[bg * 256 + tid] = v;
    }
    __syncthreads();

    // Phase D: spatial attention dot over channels
    {
        int p = tid & 255, seg = tid >> 8;  // 2 segs x 128 channels
        float s = 0.f;
#pragma unroll 8
        for (int c = 0; c < 128; ++c)
            s = fmaf(xg[(seg * 128 + c) * 256 + p], caws[seg * 128 + c], s);
        red[tid] = s;
    }
    __syncthreads();
    if (tid < 256) {
        float v = sigmoidf_(red[tid] + red[256 + tid] + sab[g]);
        sas[tid] = v;
        sa[bg * 256 + tid] = v;
    }
    __syncthreads();

    // Phase E: group sum of sigmoid(x * ca * sa)
    {
        int c = tid >> 1, h = tid & 1;
        const float* row = xg + c * 256 + h * 128;
        float k1 = cas[c];
        float s = 0.f;
#pragma unroll 4
        for (int i = 0; i < 128; ++i) {
            float t = row[i] * k1 * sas[h * 128 + i];
            s += sigmoidf_(t);
        }
        red[tid] = s;
    }
    __syncthreads();
    for (int off = 256; off > 0; off >>= 1) {
        if (tid < off) red[tid] += red[tid + off];
        __syncthreads();
    }
    if (tid == 0) gsum[bg] = red[0];
}

// out = x*(1+mask), float4-vectorized
__global__ __launch_bounds__(256) void final_kernel(
    const float* __restrict__ y4, const float* __restrict__ ca,
    const float* __restrict__ sa, const float* __restrict__ gsum,
    float* __restrict__ out)
{
    int f = blockIdx.x * 256 + threadIdx.x;   // float4 index, 1048576 total
    int p4 = f & 63, ch = (f >> 6) & 2047, b = f >> 17;
    int g = ch >> 8, c = ch & 255, bg = b * 8 + g;
    const float4 x = *(const float4*)(y4 + ((size_t)b * 512 + (g & 1) * 256 + c) * 256 + p4 * 4);
    float cav = ca[bg * 256 + c];
    const float4 sv = *(const float4*)(sa + bg * 256 + p4 * 4);
    float mean = gsum[bg] * (1.f / 65536.f);
    float4 o;
#define DOLANE(X) { float yv = sigmoidf_(x.X * cav * sv.X); float mk = (yv > mean) ? 1.f : yv; o.X = x.X * (1.f + mk); }
    DOLANE(x) DOLANE(y) DOLANE(z) DOLANE(w)
#undef DOLANE
    *(float4*)(out + (size_t)f * 4) = o;
}

extern "C" void kernel_launch(void* const* d_in, const int* in_sizes, int n_in,
                              void* d_out, int out_size, void* d_ws, size_t ws_size,
                              hipStream_t stream) {
    const float* x4   = (const float*)d_in[3];
    const float* w4   = (const float*)d_in[10];
    const float* b4   = (const float*)d_in[11];
    const float* fc1w = (const float*)d_in[12];
    const float* fc1b = (const float*)d_in[13];
    const float* fc2w = (const float*)d_in[14];
    const float* fc2b = (const float*)d_in[15];
    const float* saw  = (const float*)d_in[16];
    const float* sab  = (const float*)d_in[17];
    float* out = (float*)d_out;

    float* ws = (float*)d_ws;
    float* y4   = ws;                        // 1048576 floats
    float* ca   = ws + 1048576;              // 16384
    float* sa   = ws + 1048576 + 16384;      // 16384
    float* gsum = ws + 1048576 + 2 * 16384;  // 64
    unsigned short* wbf = (unsigned short*)(ws + 1081408);           // 1M bf16
    unsigned short* xbT = (unsigned short*)(ws + 1081408 + 524288);  // 4M bf16

    convert_w<<<dim3(1024), dim3(256), 0, stream>>>(w4, wbf);
    transpose_x<<<dim3(32, 4, 8), dim3(256), 0, stream>>>(x4, xbT);
    gemm_bf16<<<dim3(4, 8, 8), dim3(256), 0, stream>>>(wbf, xbT, b4, y4);
    att_kernel<<<dim3(64), dim3(512), 0, stream>>>(y4, fc1w, fc1b, fc2w, fc2b,
                                                   saw, sab, ca, sa, gsum);
    final_kernel<<<dim3(4096), dim3(256), 0, stream>>>(y4, ca, sa, gsum, out);
}

// Round 4
// 50.879 us; speedup vs baseline: 2.6745x; 1.5353x over previous
//
#include <hip/hip_runtime.h>
#include <math.h>

typedef __attribute__((ext_vector_type(8))) short bf16x8;
typedef __attribute__((ext_vector_type(8))) unsigned short u16x8;
typedef __attribute__((ext_vector_type(4))) float f32x4;

#define GLOAD_LDS16(g, l) __builtin_amdgcn_global_load_lds( \
    (const __attribute__((address_space(1))) unsigned int*)(g), \
    (__attribute__((address_space(3))) unsigned int*)(l), 16, 0, 0)

__device__ __forceinline__ unsigned short f2bf(float f) {
    unsigned int u = __builtin_bit_cast(unsigned int, f);
    unsigned int r = (u + 0x7FFFu + ((u >> 16) & 1)) >> 16;
    return (unsigned short)r;
}

__device__ __forceinline__ float sigmoidf_(float v) {
    return 1.f / (1.f + expf(-v));
}

// Tiled-swizzled bf16 operand layout: 64x64 tiles (4096 elems), elem (r,k)
// stored at tileBase + r*64 + ((k>>3) ^ (r&7))*8 + (k&7).  This is the exact
// linear image global_load_lds DMAs into LDS; the GEMM's ds_read applies the
// same XOR -> conflict-free (2-way only).
//
// blocks 0..511: w [512][2048] -> wbf tiles (mt*32+kt)
// blocks 512..1535: x4 [8][2048][256] -> xbf tiles: row n'=b*256+p, tile (nt*32+kt)
__global__ __launch_bounds__(256) void convert_kernel(
    const float* __restrict__ w, const float* __restrict__ x4,
    unsigned short* __restrict__ wbf, unsigned short* __restrict__ xbf)
{
    __shared__ float t[64][65];
    if (blockIdx.x < 512) {
        int f = blockIdx.x * 256 + threadIdx.x;      // ushort8 chunk id
        int tile = f >> 9, inner = f & 511;
        int r = inner >> 3, cc = inner & 7;
        int mt = tile >> 5, kt = tile & 31;
        const float* src = w + (mt * 64 + r) * 2048 + kt * 64 + cc * 8;
        float4 v0 = *(const float4*)src;
        float4 v1 = *(const float4*)(src + 4);
        u16x8 o;
        o[0] = f2bf(v0.x); o[1] = f2bf(v0.y); o[2] = f2bf(v0.z); o[3] = f2bf(v0.w);
        o[4] = f2bf(v1.x); o[5] = f2bf(v1.y); o[6] = f2bf(v1.z); o[7] = f2bf(v1.w);
        *(u16x8*)(wbf + (size_t)tile * 4096 + r * 64 + ((cc ^ (r & 7)) * 8)) = o;
        return;
    }
    // x path: LDS-transpose a 64k x 64p block, emit swizzled bf16 tile
    const int bi = blockIdx.x - 512;        // 0..1023
    const int b = bi >> 7, rem = bi & 127;
    const int kt = rem >> 2, pg = rem & 3;
    const float* src = x4 + ((size_t)b * 2048 + kt * 64) * 256 + pg * 64;
#pragma unroll
    for (int i = 0; i < 4; ++i) {
        int f = i * 256 + threadIdx.x;       // 0..1023 float4s = 64k x 64p
        int kk = f >> 4, pp4 = f & 15;       // kk 0..63, pp4 0..15
        float4 v = *(const float4*)(src + kk * 256 + pp4 * 4);
        t[pp4 * 4 + 0][kk] = v.x;
        t[pp4 * 4 + 1][kk] = v.y;
        t[pp4 * 4 + 2][kk] = v.z;
        t[pp4 * 4 + 3][kk] = v.w;
    }
    __syncthreads();
    unsigned short* dst = xbf + (size_t)((b * 4 + pg) * 32 + kt) * 4096;
#pragma unroll
    for (int i = 0; i < 2; ++i) {
        int inner = i * 256 + threadIdx.x;
        int r = inner >> 3, cc = inner & 7;
        u16x8 o;
#pragma unroll
        for (int j = 0; j < 8; ++j) o[j] = f2bf(t[r][cc * 8 + j]);
        *(u16x8*)(dst + r * 64 + ((cc ^ (r & 7)) * 8)) = o;
    }
}

// partial[ks][m][n'] = sum_{k in half ks} w[m][k] * x[n'][k]
// grid (32 nt, 8 mt, 2 ks), 256 threads (4 waves, each a 32x32 sub-tile).
__global__ __launch_bounds__(256) void gemm_bf16(
    const unsigned short* __restrict__ wbf, const unsigned short* __restrict__ xbf,
    float* __restrict__ partial)
{
    __shared__ short As[2][4096];
    __shared__ short Bs[2][4096];

    const int tid = threadIdx.x;
    const int wave = tid >> 6, lane = tid & 63;
    const int wm = wave >> 1, wn = wave & 1;
    const int lr = lane & 15, lh = lane >> 4;

    const int nt = blockIdx.x, mt = blockIdx.y, ks = blockIdx.z;

    const unsigned short* Abase = wbf + (size_t)(mt * 32 + ks * 16) * 4096;
    const unsigned short* Bbase = xbf + (size_t)(nt * 32 + ks * 16) * 4096;

    // stage tile t into buffer buf: 2 x 4096B per matrix, wave w DMAs 1024B
#define STAGE(buf, t)                                                         \
    {                                                                         \
        const unsigned short* A_ = Abase + (t) * 4096;                        \
        const unsigned short* B_ = Bbase + (t) * 4096;                        \
        _Pragma("unroll")                                                     \
        for (int q = 0; q < 2; ++q) {                                         \
            int seg = (q * 4 + wave) * 512;                                   \
            GLOAD_LDS16(A_ + seg + lane * 8, &As[buf][seg]);                  \
            GLOAD_LDS16(B_ + seg + lane * 8, &Bs[buf][seg]);                  \
        }                                                                     \
    }

    STAGE(0, 0);
    __syncthreads();

    f32x4 acc[2][2] = {};
    int cur = 0;
    for (int t = 0; t < 16; ++t) {
        if (t < 15) STAGE(cur ^ 1, t + 1);
#pragma unroll
        for (int kc = 0; kc < 2; ++kc) {
            const int ch = kc * 4 + lh;
            int rA0 = wm * 32 + lr, rA1 = rA0 + 16;
            int rB0 = wn * 32 + lr, rB1 = rB0 + 16;
            bf16x8 a0 = *(const bf16x8*)(&As[cur][rA0 * 64 + (ch ^ (rA0 & 7)) * 8]);
            bf16x8 a1 = *(const bf16x8*)(&As[cur][rA1 * 64 + (ch ^ (rA1 & 7)) * 8]);
            bf16x8 b0 = *(const bf16x8*)(&Bs[cur][rB0 * 64 + (ch ^ (rB0 & 7)) * 8]);
            bf16x8 b1 = *(const bf16x8*)(&Bs[cur][rB1 * 64 + (ch ^ (rB1 & 7)) * 8]);
            acc[0][0] = __builtin_amdgcn_mfma_f32_16x16x32_bf16(a0, b0, acc[0][0], 0, 0, 0);
            acc[0][1] = __builtin_amdgcn_mfma_f32_16x16x32_bf16(a0, b1, acc[0][1], 0, 0, 0);
            acc[1][0] = __builtin_amdgcn_mfma_f32_16x16x32_bf16(a1, b0, acc[1][0], 0, 0, 0);
            acc[1][1] = __builtin_amdgcn_mfma_f32_16x16x32_bf16(a1, b1, acc[1][1], 0, 0, 0);
        }
        __syncthreads();
        cur ^= 1;
    }
#undef STAGE

    float* pb = partial + ((size_t)ks * 512 + mt * 64) * 2048 + nt * 64;
#pragma unroll
    for (int i = 0; i < 2; ++i)
#pragma unroll
        for (int j = 0; j < 2; ++j)
#pragma unroll
            for (int rr = 0; rr < 4; ++rr) {
                int m = wm * 32 + i * 16 + lh * 4 + rr;
                int n = wn * 32 + j * 16 + lr;
                pb[m * 2048 + n] = acc[i][j][rr];
            }
}

// y4[b][m][p] = partial0 + partial1 + bias[m]; also per-(b,m) channel mean.
__global__ __launch_bounds__(256) void reduce_bias(
    const float* __restrict__ partial, const float* __restrict__ bias,
    float* __restrict__ y4, float* __restrict__ chansum)
{
    int f = blockIdx.x * 256 + threadIdx.x;    // float4 id, 0..262143
    int m = f >> 9, n4 = f & 511;
    float4 a = ((const float4*)partial)[f];
    float4 c = ((const float4*)partial)[f + 262144];
    float bv = bias[m];
    float4 o;
    o.x = a.x + c.x + bv; o.y = a.y + c.y + bv;
    o.z = a.z + c.z + bv; o.w = a.w + c.w + bv;
    int b = n4 >> 6, p4 = n4 & 63;
    *(float4*)(y4 + ((size_t)(b * 512 + m)) * 256 + p4 * 4) = o;
    // wave (64 lanes) covers exactly the 256 positions of one (b,m)
    float s = o.x + o.y + o.z + o.w;
#pragma unroll
    for (int off = 32; off > 0; off >>= 1) s += __shfl_down(s, off);
    if ((threadIdx.x & 63) == 0) chansum[b * 512 + m] = s * (1.f / 256.f);
}

// Per (bg, p-chunk of 32): fc1+fc2 (redundant per chunk, cheap), sa dot over
// 256 channels, deterministic gsum partial.  512 blocks x 256 threads.
__global__ __launch_bounds__(256) void sa_kernel(
    const float* __restrict__ y4, const float* __restrict__ chansum,
    const float* __restrict__ fc1w, const float* __restrict__ fc1b,
    const float* __restrict__ fc2w, const float* __restrict__ fc2b,
    const float* __restrict__ saw, const float* __restrict__ sab,
    float* __restrict__ ca, float* __restrict__ sa, float* __restrict__ gsums)
{
    const int blk = blockIdx.x;
    const int bg = blk >> 3, pc = blk & 7;
    const int b = bg >> 3, g = bg & 7;
    const int tid = threadIdx.x;
    const float* xg = y4 + ((size_t)b * 512 + (g & 1) * 256) * 256;

    __shared__ float avgs[256], red[256], hs[64], cas[256], caws[256], sas[32];

    avgs[tid] = chansum[b * 512 + (g & 1) * 256 + tid];
    __syncthreads();
    // fc1: 256 -> 64, relu
    {
        int o = tid & 63, seg = tid >> 6;
        const float* wr = fc1w + (g * 64 + o) * 256 + seg * 64;
        const float* av = avgs + seg * 64;
        float s = 0.f;
#pragma unroll
        for (int i = 0; i < 64; ++i) s = fmaf(av[i], wr[i], s);
        red[tid] = s;
    }
    __syncthreads();
    if (tid < 64) {
        float s = fc1b[g * 64 + tid] + red[tid] + red[64 + tid] + red[128 + tid] + red[192 + tid];
        hs[tid] = fmaxf(s, 0.f);
    }
    __syncthreads();
    // fc2: 64 -> 256, sigmoid
    {
        const float* wr = fc2w + (g * 256 + tid) * 64;
        float s = fc2b[g * 256 + tid];
#pragma unroll
        for (int i = 0; i < 64; ++i) s = fmaf(hs[i], wr[i], s);
        float v = sigmoidf_(s);
        cas[tid] = v;
        caws[tid] = v * saw[g * 256 + tid];
        if (pc == 0) ca[bg * 256 + tid] = v;
    }
    __syncthreads();
    // sa dot over channels for 32 positions
    const int p_l = tid & 31, seg8 = tid >> 5;
    const int p = pc * 32 + p_l;
    {
        float s = 0.f;
#pragma unroll
        for (int i = 0; i < 32; ++i) {
            int c = seg8 * 32 + i;
            s = fmaf(xg[c * 256 + p], caws[c], s);
        }
        red[tid] = s;
    }
    __syncthreads();
    if (tid < 32) {
        float s = sab[g];
#pragma unroll
        for (int k = 0; k < 8; ++k) s += red[k * 32 + tid];
        float v = sigmoidf_(s);
        sas[tid] = v;
        sa[bg * 256 + pc * 32 + tid] = v;
    }
    __syncthreads();
    // gsum partial: sum sigmoid(x*ca*sa) over this chunk's 32p x 256c
    {
        float sv = sas[p_l];
        float s = 0.f;
#pragma unroll
        for (int i = 0; i < 32; ++i) {
            int c = seg8 * 32 + i;
            s += sigmoidf_(xg[c * 256 + p] * cas[c] * sv);
        }
        red[tid] = s;
    }
    __syncthreads();
    for (int off = 128; off > 0; off >>= 1) {
        if (tid < off) red[tid] += red[tid + off];
        __syncthreads();
    }
    if (tid == 0) gsums[blk] = red[0];
}

// out = x*(1+mask); mask = (y>mean)?1:y, y = sigmoid(x*ca*sa)
__global__ __launch_bounds__(256) void final_kernel(
    const float* __restrict__ y4, const float* __restrict__ ca,
    const float* __restrict__ sa, const float* __restrict__ gsums,
    float* __restrict__ out)
{
    int f = blockIdx.x * 256 + threadIdx.x;   // float4 index, 1048576 total
    int p4 = f & 63, ch = (f >> 6) & 2047, b = f >> 17;
    int g = ch >> 8, c = ch & 255, bg = b * 8 + g;
    const float4 x = *(const float4*)(y4 + ((size_t)b * 512 + (g & 1) * 256 + c) * 256 + p4 * 4);
    float cav = ca[bg * 256 + c];
    const float4 sv = *(const float4*)(sa + bg * 256 + p4 * 4);
    float msum = 0.f;
#pragma unroll
    for (int i = 0; i < 8; ++i) msum += gsums[bg * 8 + i];
    float mean = msum * (1.f / 65536.f);
    float4 o;
#define DOLANE(X) { float yv = sigmoidf_(x.X * cav * sv.X); float mk = (yv > mean) ? 1.f : yv; o.X = x.X * (1.f + mk); }
    DOLANE(x) DOLANE(y) DOLANE(z) DOLANE(w)
#undef DOLANE
    *(float4*)(out + (size_t)f * 4) = o;
}

extern "C" void kernel_launch(void* const* d_in, const int* in_sizes, int n_in,
                              void* d_out, int out_size, void* d_ws, size_t ws_size,
                              hipStream_t stream) {
    const float* x4   = (const float*)d_in[3];
    const float* w4   = (const float*)d_in[10];
    const float* b4   = (const float*)d_in[11];
    const float* fc1w = (const float*)d_in[12];
    const float* fc1b = (const float*)d_in[13];
    const float* fc2w = (const float*)d_in[14];
    const float* fc2b = (const float*)d_in[15];
    const float* saw  = (const float*)d_in[16];
    const float* sab  = (const float*)d_in[17];
    float* out = (float*)d_out;

    float* ws = (float*)d_ws;
    float* y4      = ws;                    // 1048576
    float* ca      = ws + 1048576;          // 16384
    float* sa      = ws + 1064960;          // 16384
    float* gsums   = ws + 1081344;          // 512
    float* chansum = ws + 1081856;          // 4096
    float* partial = ws + 1085952;          // 2097152
    unsigned short* wbf = (unsigned short*)(ws + 3183104);  // 1M bf16
    unsigned short* xbf = (unsigned short*)(ws + 3707392);  // 4M bf16

    convert_kernel<<<dim3(1536), dim3(256), 0, stream>>>(w4, x4, wbf, xbf);
    gemm_bf16<<<dim3(32, 8, 2), dim3(256), 0, stream>>>(wbf, xbf, partial);
    reduce_bias<<<dim3(1024), dim3(256), 0, stream>>>(partial, b4, y4, chansum);
    sa_kernel<<<dim3(512), dim3(256), 0, stream>>>(y4, chansum, fc1w, fc1b, fc2w, fc2b,
                                                   saw, sab, ca, sa, gsums);
    final_kernel<<<dim3(4096), dim3(256), 0, stream>>>(y4, ca, sa, gsums, out);
}